// Round 9
// baseline (155.082 us; speedup 1.0000x reference)
//
#include <hip/hip_runtime.h>
#include <hip/hip_bf16.h>
#include <stdint.h>

// B=2, N=2048, DIM=1024, HEADS=8, DIM_HEAD=64, INNER=512
// Round 18: round-17's smaller-tile fix REGRESSED (+6us: doubled operand
// traffic, worse loads:MFMA ratio). Revert K3/K5 to round-14 shapes
// (K3 384x256 4-wave 2x2 128x128 block; K5 256x256) and instead fix the
// latency exposure IN-WAVE: gemm_core 3-stage -> 4-STAGE register pipeline
// (prefetch kc+3; ~216 VGPR, occupancy unchanged at 2 waves/SIMD cap;
// +50% latency coverage, no added traffic). Per-element kc-chain order
// unchanged -> bitwise-identical output (absmax 1.831e-4).
// K4 untouched. K1 stats unroll 16 retained.

#define B_ 2
#define N_ 2048
#define DIM_ 1024
#define DH_ 64
#define INNER_ 512
#define ROWS_ 4096
#define BHSTRIDE 131072    // 2048*64 elems per (b,h) for qf/kf/vf

// q scale 1/8 (=DH^-0.5) * log2(e), folded into wq cast; kernel uses exp2.
#define QSCALE 0.18033688011112042f

typedef __bf16 bf16x8 __attribute__((ext_vector_type(8)));
typedef float floatx4 __attribute__((ext_vector_type(4)));

#if __has_builtin(__builtin_amdgcn_exp2f)
#define EXP2(x) __builtin_amdgcn_exp2f(x)
#else
#define EXP2(x) exp2f(x)
#endif

// HW bf16 conversion (RNE).
__device__ __forceinline__ ushort f2bf(float f) {
    union { __bf16 h; ushort u; } v;
    v.h = (__bf16)f;
    return v.u;
}
#if __has_builtin(__builtin_amdgcn_cvt_pk_bf16_f32)
__device__ __forceinline__ uint32_t pkbf(float a, float b) {
    auto h = __builtin_amdgcn_cvt_pk_bf16_f32(a, b);
    union { decltype(h) h; uint32_t u; } v;
    v.h = h;
    return v.u;
}
#else
__device__ __forceinline__ uint32_t pkbf(float a, float b) {
    return (uint32_t)f2bf(a) | ((uint32_t)f2bf(b) << 16);
}
#endif

// frag-major element offset: lane l of a wave holds M=16*T+(l&15),
// k = 32*kc + 8*(l>>4) + j  (j=0..7). nkc = K/32.
__device__ __forceinline__ size_t frag_off(int m, int k, int nkc) {
    return ((size_t)((m >> 4) * nkc + (k >> 5)) * 64 +
            (size_t)((m & 15) | (((k >> 3) & 3) << 4))) * 8 + (k & 7);
}

// ---------------------------------------------------------------------------
// K1: fused setup. blocks 0..255: partial column stats (seq axis).
// blocks 256..2303: weight cast into frag-major layouts.
__global__ __launch_bounds__(256) void setup_fused(
    const float* __restrict__ x, float* __restrict__ ps, float* __restrict__ pq,
    const float* __restrict__ wq, const float* __restrict__ wkv,
    const float* __restrict__ wo, ushort* __restrict__ wqkv_f,
    ushort* __restrict__ wo_f) {
    __shared__ float tile[32][33];
    int bid = blockIdx.x;
    if (bid < 256) {
        int gd = (bid & 7) * 256 + threadIdx.x;   // b*1024 + c
        int ch = bid >> 3;                        // 0..31
        int b = gd >> 10;
        const float* p = x + (size_t)(b * N_ + ch * 64) * DIM_ + (gd & 1023);
        float s = 0.f, q = 0.f;
#pragma unroll 16
        for (int n = 0; n < 64; ++n) { float v = p[(size_t)n * DIM_]; s += v; q += v * v; }
        ps[ch * 2048 + gd] = s;
        pq[ch * 2048 + gd] = q;
        return;
    }
    int t = bid - 256;
    const float* src; ushort* dst; int C, K, k0, ncol0, nglob0; float scale;
    if (t < 512) {
        int kt = t >> 4, nt = t & 15;
        src = wq; dst = wqkv_f; C = 512; K = 1024; scale = QSCALE;
        k0 = kt * 32; ncol0 = nt * 32; nglob0 = ncol0;
    } else if (t < 1536) {
        int u = t - 512; int kt = u >> 5, nt = u & 31;
        src = wkv; dst = wqkv_f; C = 1024; K = 1024; scale = 1.f;
        k0 = kt * 32; ncol0 = nt * 32; nglob0 = 512 + ncol0;
    } else {
        int u = t - 1536; int kt = u >> 5, nt = u & 31;
        src = wo; dst = wo_f; C = 1024; K = 512; scale = 1.f;
        k0 = kt * 32; ncol0 = nt * 32; nglob0 = ncol0;
    }
    int ti = threadIdx.x >> 5, tj = threadIdx.x & 31;
#pragma unroll
    for (int p = 0; p < 4; ++p)
        tile[ti + 8 * p][tj] = src[(size_t)(k0 + ti + 8 * p) * C + ncol0 + tj] * scale;
    __syncthreads();
    if (threadIdx.x < 128) {
        int nl = threadIdx.x & 31, kc8 = threadIdx.x >> 5;
        union { ushort us[8]; uint4 v; } u;
#pragma unroll
        for (int ii = 0; ii < 8; ++ii) u.us[ii] = f2bf(tile[kc8 * 8 + ii][nl]);
        *(uint4*)&dst[frag_off(nglob0 + nl, k0 + kc8 * 8, K >> 5)] = u.v;
    }
}

// ---------------------------------------------------------------------------
// K2: fused finalize + normalize + cast to frag-major xn. grid 512, block 256.
__global__ __launch_bounds__(256) void finalize_norm(
    const float* __restrict__ ps, const float* __restrict__ pq,
    const float* __restrict__ x, const float* __restrict__ g,
    ushort* __restrict__ xnf) {
    __shared__ float s4[4][64], q4[4][64], aa[64], bb[64];
    int t = threadIdx.x;
    int b = blockIdx.x >> 8, slab = (blockIdx.x >> 4) & 15, nch = blockIdx.x & 15;
    int c0 = slab * 64;
    {
        int c = t & 63, grp = t >> 6;
        float s = 0.f, q = 0.f;
#pragma unroll
        for (int ch = 0; ch < 8; ++ch) {
            int o = (grp * 8 + ch) * 2048 + b * 1024 + c0 + c;
            s += ps[o]; q += pq[o];
        }
        s4[grp][c] = s; q4[grp][c] = q;
    }
    __syncthreads();
    if (t < 64) {
        float s = s4[0][t] + s4[1][t] + s4[2][t] + s4[3][t];
        float q = q4[0][t] + q4[1][t] + q4[2][t] + q4[3][t];
        float mean = s * (1.f / N_);
        float var = q * (1.f / N_) - mean * mean;
        float rstd = rsqrtf(var + 1e-5f);
        float a = rstd * g[c0 + t];
        aa[t] = a; bb[t] = -mean * a;
    }
    __syncthreads();
    int c4 = (t & 15) * 4, ro = t >> 4;
#pragma unroll
    for (int it = 0; it < 8; ++it) {
        int r = nch * 128 + it * 16 + ro;
        int m = b * 2048 + r;
        float4 xv = *(const float4*)&x[(size_t)m * DIM_ + c0 + c4];
        float v0 = xv.x * aa[c4 + 0] + bb[c4 + 0];
        float v1 = xv.y * aa[c4 + 1] + bb[c4 + 1];
        float v2 = xv.z * aa[c4 + 2] + bb[c4 + 2];
        float v3 = xv.w * aa[c4 + 3] + bb[c4 + 3];
        uint2 u; u.x = pkbf(v0, v1); u.y = pkbf(v2, v3);
        *(uint2*)&xnf[frag_off(m, c0 + c4, 32)] = u;
    }
}

// ---------------------------------------------------------------------------
// LDS-free GEMM core: ROLLED 4-STAGE register pipeline (round 18).
// Prefetch kc+3 ahead; NKC must be divisible by 4 (32 and 16 both are).
// Per-acc-element kc accumulation order identical to 3-stage version.
template <int NKC>
__device__ __forceinline__ void gemm_core(
    const ushort* __restrict__ pA, const ushort* __restrict__ pB,
    floatx4 (&acc)[4][4]) {
    constexpr int TS = NKC * 512;
    bf16x8 a0[4], b0[4], a1[4], b1[4], a2[4], b2[4], a3[4], b3[4];
    auto ld = [&](bf16x8 (&a)[4], bf16x8 (&b)[4], int kc) {
#pragma unroll
        for (int i = 0; i < 4; ++i) {
            a[i] = *(const bf16x8*)(pA + (size_t)i * TS + (size_t)kc * 512);
            b[i] = *(const bf16x8*)(pB + (size_t)i * TS + (size_t)kc * 512);
        }
    };
    auto mm = [&](bf16x8 (&a)[4], bf16x8 (&b)[4]) {
#pragma unroll
        for (int mi = 0; mi < 4; ++mi)
#pragma unroll
            for (int ni = 0; ni < 4; ++ni)
                acc[mi][ni] = __builtin_amdgcn_mfma_f32_16x16x32_bf16(
                    a[mi], b[ni], acc[mi][ni], 0, 0, 0);
    };
    ld(a0, b0, 0);
    ld(a1, b1, 1);
    ld(a2, b2, 2);
    int kc = 0;
    for (; kc + 4 <= NKC; kc += 4) {
        ld(a3, b3, kc + 3);
        mm(a0, b0);
        if (kc + 4 < NKC) ld(a0, b0, kc + 4);
        mm(a1, b1);
        if (kc + 5 < NKC) ld(a1, b1, kc + 5);
        mm(a2, b2);
        if (kc + 6 < NKC) ld(a2, b2, kc + 6);
        mm(a3, b3);
    }
    // NKC % 4 == 0 for all instantiations (32, 16): no remainder.
}

// K3: qkv GEMM. 1D grid 384, block 256 (4 waves, 2x2): 128x128 per block;
// waves pair-share A and B via L1. XCD swizzle: XCD j owns bx slab.
__global__ __launch_bounds__(256) void gemm_qkv(
    const ushort* __restrict__ xnf, const ushort* __restrict__ wf,
    ushort* __restrict__ qf, ushort* __restrict__ kf, ushort* __restrict__ vf) {
    int tx = threadIdx.x, w = tx >> 6, l = tx & 63;
    int wr = w >> 1, wc = w & 1;
    int lr = l & 15, lq = l >> 4;
    int bid = blockIdx.x;
    int xcd = bid & 7, t = bid >> 3;          // t: 0..47
    int bx = xcd * 4 + (t & 3);               // 0..31 (128-row slab)
    int by = t >> 2;                          // 0..11
    int rx = bx * 2 + wr;                     // 0..63 (64-row slab)
    const ushort* pA = xnf + (size_t)(rx * 4) * 32 * 512 + l * 8;
    const ushort* pB = wf + (size_t)(by * 8 + wc * 4) * 32 * 512 + l * 8;
    floatx4 acc[4][4] = {};
    gemm_core<32>(pA, pB, acc);
    int col0 = by * 128 + wc * 64;
    int bb2 = (rx * 64) >> 11;
    if (by < 8) {
        ushort* qkbase = (by < 4) ? qf : kf;
#pragma unroll
        for (int ni = 0; ni < 4; ++ni) {
            int col = col0 + 16 * ni + lr;
            int hh = (col >> 6) & 7, d = col & 63;
            ushort* base = qkbase + (size_t)(bb2 * 8 + hh) * BHSTRIDE
                           + (d >> 5) * 512 + ((d >> 3) & 3) * 128 + (d & 7)
                           + (4 * lq) * 8;
#pragma unroll
            for (int mi = 0; mi < 4; ++mi) {
                size_t o2 = (size_t)((rx * 4 + mi) & 127) * 1024;
#pragma unroll
                for (int reg = 0; reg < 4; ++reg)
                    base[o2 + reg * 8] = f2bf(acc[mi][ni][reg]);
            }
        }
    } else {
#pragma unroll
        for (int ni = 0; ni < 4; ++ni) {
            int cv = col0 - 1024 + 16 * ni + lr;
            int hh = cv >> 6, d = cv & 63;
            ushort* base = vf + (size_t)(bb2 * 8 + hh) * BHSTRIDE
                           + (d >> 4) * 32768 + (d & 15) * 8;
#pragma unroll
            for (int mi = 0; mi < 4; ++mi) {
                int nn = (rx * 64 + 16 * mi + 4 * lq) & 2047;
                uint2 u;
                u.x = pkbf(acc[mi][ni][0], acc[mi][ni][1]);
                u.y = pkbf(acc[mi][ni][2], acc[mi][ni][3]);
                *(uint2*)&base[(nn >> 5) * 512 + ((nn >> 3) & 3) * 128 + (nn & 7)] = u;
            }
        }
    }
}

// K5: out GEMM. 1D grid 256, block 256 (4 waves, 2x2): 128x128 per block.
__global__ __launch_bounds__(256) void gemm_out(
    const ushort* __restrict__ af, const ushort* __restrict__ wf,
    float* __restrict__ out) {
    int tx = threadIdx.x, w = tx >> 6, l = tx & 63;
    int wr = w >> 1, wc = w & 1;
    int lr = l & 15, lq = l >> 4;
    int bid = blockIdx.x;
    int xcd = bid & 7, t = bid >> 3;          // t: 0..31
    int bx = xcd * 4 + (t & 3);               // 0..31 (128-row slab)
    int by = t >> 2;                          // 0..7
    int rx = bx * 2 + wr;                     // 0..63
    const ushort* pA = af + (size_t)(rx * 4) * 16 * 512 + l * 8;
    const ushort* pB = wf + (size_t)(by * 8 + wc * 4) * 16 * 512 + l * 8;
    floatx4 acc[4][4] = {};
    gemm_core<16>(pA, pB, acc);
    int col0 = by * 128 + wc * 64;
#pragma unroll
    for (int mi = 0; mi < 4; ++mi)
#pragma unroll
        for (int ni = 0; ni < 4; ++ni) {
            int col = col0 + 16 * ni + lr;
#pragma unroll
            for (int reg = 0; reg < 4; ++reg) {
                int row = rx * 64 + 16 * mi + 4 * lq + reg;
                out[(size_t)row * 1024 + col] = acc[mi][ni][reg];
            }
        }
}

// ---------------------------------------------------------------------------
// K4: flash, 128 q-rows per block. 256 blocks x 512 thr (8 waves).
// Wave w: q-subtile qsel=w>>2 (64 rows), key-quarter kq=w&3 (512 keys).
__global__ __launch_bounds__(512, 2) void flash_attn(
    const ushort* __restrict__ qf, const ushort* __restrict__ kf,
    const ushort* __restrict__ vf, ushort* __restrict__ attnf) {
    __shared__ __align__(16) float sArena[8 * 4352];  // P (loop) / O 64x68 (merge)
    __shared__ float sL[8][64];

    const int tx = threadIdx.x;
    const int w = tx >> 6, l = tx & 63;      // w: 0..7
    const int qsel = w >> 2, kq = w & 3;
    const int lr = l & 15, lq = l >> 4;
    const int bid = blockIdx.x;              // 0..255
    const int bh = (bid & 7) * 2 + ((bid >> 3) & 1);
    const int qt = bid >> 4;                 // 0..15 (tile of 128 q rows)

    const ushort* qfb = qf + (size_t)bh * BHSTRIDE
                        + (size_t)(qt * 8 + qsel * 4) * 1024 + l * 8;
    const ushort* kfb = kf + (size_t)bh * BHSTRIDE + (size_t)kq * 32768 + l * 8;
    const ushort* vfb = vf + (size_t)bh * BHSTRIDE + (size_t)kq * 8192 + l * 8;
    ushort* sPw = (ushort*)(sArena + w * 4352);

    bf16x8 bq[4][2];
#pragma unroll
    for (int qq = 0; qq < 4; ++qq)
#pragma unroll
        for (int s = 0; s < 2; ++s)
            bq[qq][s] = *(const bf16x8*)(qfb + qq * 1024 + s * 512);

    floatx4 o[4][4] = {};
    float lsum[4] = {0.f, 0.f, 0.f, 0.f};

    bf16x8 ak[8], bv[8];
#pragma unroll
    for (int kk = 0; kk < 4; ++kk) {
        ak[kk * 2 + 0] = *(const bf16x8*)(kfb + kk * 1024);
        ak[kk * 2 + 1] = *(const bf16x8*)(kfb + kk * 1024 + 512);
    }

    for (int kt = 0; kt < 8; ++kt) {
#pragma unroll
        for (int dt = 0; dt < 4; ++dt) {
            bv[dt * 2 + 0] = *(const bf16x8*)(vfb + dt * 32768 + (kt * 2 + 0) * 512);
            bv[dt * 2 + 1] = *(const bf16x8*)(vfb + dt * 32768 + (kt * 2 + 1) * 512);
        }

        // QK^T + softmax-exp in two kk-halves (lsum order kk-ascending =
        // bitwise identical across rounds).
#pragma unroll
        for (int h = 0; h < 2; ++h) {
            floatx4 c[2][4] = {};
            __builtin_amdgcn_s_setprio(1);
#pragma unroll
            for (int s = 0; s < 2; ++s)
#pragma unroll
                for (int kk = 0; kk < 2; ++kk)
#pragma unroll
                    for (int qq = 0; qq < 4; ++qq)
                        c[kk][qq] = __builtin_amdgcn_mfma_f32_16x16x32_bf16(
                            ak[(2 * h + kk) * 2 + s], bq[qq][s], c[kk][qq], 0, 0, 0);
            __builtin_amdgcn_s_setprio(0);

            // ak dead after half 1's MFMAs: prefetch next K-tile here so the
            // loads' latency hides under half-1 exp + PV.
            if (h == 1 && kt + 1 < 8) {
                const ushort* kp = kfb + (size_t)(kt + 1) * 4096;
#pragma unroll
                for (int kk = 0; kk < 4; ++kk) {
                    ak[kk * 2 + 0] = *(const bf16x8*)(kp + kk * 1024);
                    ak[kk * 2 + 1] = *(const bf16x8*)(kp + kk * 1024 + 512);
                }
            }

#pragma unroll
            for (int kk = 0; kk < 2; ++kk)
#pragma unroll
                for (int qq = 0; qq < 4; ++qq) {
                    float e0 = EXP2(c[kk][qq][0]);
                    float e1 = EXP2(c[kk][qq][1]);
                    float e2 = EXP2(c[kk][qq][2]);
                    float e3 = EXP2(c[kk][qq][3]);
                    lsum[qq] += (e0 + e1) + (e2 + e3);
                    uint2 u; u.x = pkbf(e0, e1); u.y = pkbf(e2, e3);
                    *(uint2*)&sPw[(16 * qq + lr) * 72 + 16 * (2 * h + kk) + 4 * lq] = u;
                }
        }

#pragma unroll
        for (int s = 0; s < 2; ++s) {
            bf16x8 ap[4];
#pragma unroll
            for (int mi = 0; mi < 4; ++mi)
                ap[mi] = *(const bf16x8*)&sPw[(16 * mi + lr) * 72 + 32 * s + 8 * lq];
            __builtin_amdgcn_s_setprio(1);
#pragma unroll
            for (int mi = 0; mi < 4; ++mi)
#pragma unroll
                for (int dt = 0; dt < 4; ++dt)
                    o[mi][dt] = __builtin_amdgcn_mfma_f32_16x16x32_bf16(
                        ap[mi], bv[dt * 2 + s], o[mi][dt], 0, 0, 0);
            __builtin_amdgcn_s_setprio(0);
        }
    }

#pragma unroll
    for (int qq = 0; qq < 4; ++qq) {
        lsum[qq] += __shfl_xor(lsum[qq], 16);
        lsum[qq] += __shfl_xor(lsum[qq], 32);
    }

    float* Rw = sArena + w * 4352;
#pragma unroll
    for (int mi = 0; mi < 4; ++mi)
#pragma unroll
        for (int dt = 0; dt < 4; ++dt)
#pragma unroll
            for (int reg = 0; reg < 4; ++reg)
                Rw[(16 * mi + 4 * lq + reg) * 68 + 16 * dt + lr] = o[mi][dt][reg];
    if (lq == 0) {
#pragma unroll
        for (int qq = 0; qq < 4; ++qq) sL[w][16 * qq + lr] = lsum[qq];
    }
    __syncthreads();

    // Merge group g = qsel handles q-subtile g: arenas g*4 + rg, rg = 0..3
    // (same key-quarter order -> identical summation order).
    const int g = qsel;
    int qloc = 16 * (w & 3) + (l >> 2);
    int c0 = (l & 3) * 16;
    float4 acc[4];
#pragma unroll
    for (int rg = 0; rg < 4; ++rg) {
        const float* R = sArena + (g * 4 + rg) * 4352 + qloc * 68 + c0;
#pragma unroll
        for (int c = 0; c < 4; ++c) {
            float4 v = *(const float4*)&R[4 * c];
            if (rg == 0) acc[c] = v;
            else { acc[c].x += v.x; acc[c].y += v.y; acc[c].z += v.z; acc[c].w += v.w; }
        }
    }
    float ltot = sL[g * 4 + 0][qloc] + sL[g * 4 + 1][qloc]
               + sL[g * 4 + 2][qloc] + sL[g * 4 + 3][qloc];
    float inv = 1.f / ltot;
    int m = (bh >> 3) * 2048 + qt * 128 + g * 64 + qloc;
    int kb = (bh & 7) * 64 + c0;
#pragma unroll
    for (int c = 0; c < 4; ++c) {
        uint2 u;
        u.x = pkbf(acc[c].x * inv, acc[c].y * inv);
        u.y = pkbf(acc[c].z * inv, acc[c].w * inv);
        *(uint2*)&attnf[frag_off(m, kb + 4 * c, 16)] = u;
    }
}

// ---------------------------------------------------------------------------
extern "C" void kernel_launch(void* const* d_in, const int* in_sizes, int n_in,
                              void* d_out, int out_size, void* d_ws, size_t ws_size,
                              hipStream_t stream) {
    const float* x   = (const float*)d_in[0];
    const float* g   = (const float*)d_in[1];
    const float* wq  = (const float*)d_in[2];
    const float* wkv = (const float*)d_in[3];
    const float* wo  = (const float*)d_in[4];
    float* out = (float*)d_out;

    char* ws = (char*)d_ws;
    float*  psum   = (float*)(ws + 0);          // 256K
    float*  psqr   = (float*)(ws + 262144);     // 256K
    ushort* xnf    = (ushort*)(ws + 524288);    // 8.39M frag-major K=1024
    ushort* wqkv_f = (ushort*)(ws + 8912896);   // 3.15M frag-major K=1024
    ushort* wo_f   = (ushort*)(ws + 12058624);  // 1.05M frag-major K=512
    ushort* qfb    = (ushort*)(ws + 13107200);  // 4.19M per-bh frag [row][d]
    ushort* kfb    = (ushort*)(ws + 17301504);  // 4.19M per-bh frag [row][d]
    ushort* vfb    = (ushort*)(ws + 21495808);  // 4.19M per-bh frag [d][key]
    ushort* attnf  = (ushort*)(ws + 25690112);  // 4.19M frag-major K=512

    setup_fused<<<2304, 256, 0, stream>>>(x, psum, psqr, wq, wkv, wo, wqkv_f, wo_f);
    finalize_norm<<<512, 256, 0, stream>>>(psum, psqr, x, g, xnf);
    gemm_qkv<<<384, 256, 0, stream>>>(xnf, wqkv_f, qfb, kfb, vfb);
    flash_attn<<<256, 512, 0, stream>>>(qfb, kfb, vfb, attnf);
    gemm_out<<<256, 256, 0, stream>>>(attnf, wo_f, out);
}

// Round 11
// 142.824 us; speedup vs baseline: 1.0858x; 1.0858x over previous
//
#include <hip/hip_runtime.h>
#include <hip/hip_bf16.h>
#include <stdint.h>

// B=2, N=2048, DIM=1024, HEADS=8, DIM_HEAD=64, INNER=512
// Round 19 (2nd submit; container-infra failure on first attempt — same
// signature as rounds 1-2 which resolved on resubmit; code identical):
// K3 K-loop -> m97 structure: double-buffered LDS +
// __builtin_amdgcn_global_load_lds width=16, T3-minimum 2-phase loop
// (stage next || ds_read+MFMA cur, one vmcnt-drain barrier per K-step).
// Frag-major layout makes each staged chunk 64 lanes x 16B contiguous:
// DMA linear dest == frag layout; ds_read_b128 at l*16B is conflict-free.
// MFMA per-element kc order unchanged -> bitwise-identical output.
// Everything else is round-14 exactly (best measured 140.4).

#define B_ 2
#define N_ 2048
#define DIM_ 1024
#define DH_ 64
#define INNER_ 512
#define ROWS_ 4096
#define BHSTRIDE 131072    // 2048*64 elems per (b,h) for qf/kf/vf

// q scale 1/8 (=DH^-0.5) * log2(e), folded into wq cast; kernel uses exp2.
#define QSCALE 0.18033688011112042f

typedef __bf16 bf16x8 __attribute__((ext_vector_type(8)));
typedef float floatx4 __attribute__((ext_vector_type(4)));

#if __has_builtin(__builtin_amdgcn_exp2f)
#define EXP2(x) __builtin_amdgcn_exp2f(x)
#else
#define EXP2(x) exp2f(x)
#endif

// HW bf16 conversion (RNE).
__device__ __forceinline__ ushort f2bf(float f) {
    union { __bf16 h; ushort u; } v;
    v.h = (__bf16)f;
    return v.u;
}
#if __has_builtin(__builtin_amdgcn_cvt_pk_bf16_f32)
__device__ __forceinline__ uint32_t pkbf(float a, float b) {
    auto h = __builtin_amdgcn_cvt_pk_bf16_f32(a, b);
    union { decltype(h) h; uint32_t u; } v;
    v.h = h;
    return v.u;
}
#else
__device__ __forceinline__ uint32_t pkbf(float a, float b) {
    return (uint32_t)f2bf(a) | ((uint32_t)f2bf(b) << 16);
}
#endif

// Async global->LDS, 16B/lane. Contract: g = per-lane source (already
// includes lane*8 elems); s = WAVE-UNIFORM chunk base; HW writes 16B to
// s + lane*16. Fallback replicates the same addressing synchronously.
#if __has_builtin(__builtin_amdgcn_global_load_lds)
__device__ __forceinline__ void gld_lds16(const ushort* g, ushort* s) {
    __builtin_amdgcn_global_load_lds(
        (const __attribute__((address_space(1))) unsigned int*)g,
        (__attribute__((address_space(3))) unsigned int*)s, 16, 0, 0);
}
#else
__device__ __forceinline__ void gld_lds16(const ushort* g, ushort* s) {
    int l = threadIdx.x & 63;
    *(uint4*)(s + l * 8) = *(const uint4*)g;
}
#endif

// frag-major element offset: lane l of a wave holds M=16*T+(l&15),
// k = 32*kc + 8*(l>>4) + j  (j=0..7). nkc = K/32.
__device__ __forceinline__ size_t frag_off(int m, int k, int nkc) {
    return ((size_t)((m >> 4) * nkc + (k >> 5)) * 64 +
            (size_t)((m & 15) | (((k >> 3) & 3) << 4))) * 8 + (k & 7);
}

// ---------------------------------------------------------------------------
// K1: fused setup. blocks 0..255: partial column stats (seq axis).
// blocks 256..2303: weight cast into frag-major layouts.
__global__ __launch_bounds__(256) void setup_fused(
    const float* __restrict__ x, float* __restrict__ ps, float* __restrict__ pq,
    const float* __restrict__ wq, const float* __restrict__ wkv,
    const float* __restrict__ wo, ushort* __restrict__ wqkv_f,
    ushort* __restrict__ wo_f) {
    __shared__ float tile[32][33];
    int bid = blockIdx.x;
    if (bid < 256) {
        int gd = (bid & 7) * 256 + threadIdx.x;   // b*1024 + c
        int ch = bid >> 3;                        // 0..31
        int b = gd >> 10;
        const float* p = x + (size_t)(b * N_ + ch * 64) * DIM_ + (gd & 1023);
        float s = 0.f, q = 0.f;
#pragma unroll 16
        for (int n = 0; n < 64; ++n) { float v = p[(size_t)n * DIM_]; s += v; q += v * v; }
        ps[ch * 2048 + gd] = s;
        pq[ch * 2048 + gd] = q;
        return;
    }
    int t = bid - 256;
    const float* src; ushort* dst; int C, K, k0, ncol0, nglob0; float scale;
    if (t < 512) {
        int kt = t >> 4, nt = t & 15;
        src = wq; dst = wqkv_f; C = 512; K = 1024; scale = QSCALE;
        k0 = kt * 32; ncol0 = nt * 32; nglob0 = ncol0;
    } else if (t < 1536) {
        int u = t - 512; int kt = u >> 5, nt = u & 31;
        src = wkv; dst = wqkv_f; C = 1024; K = 1024; scale = 1.f;
        k0 = kt * 32; ncol0 = nt * 32; nglob0 = 512 + ncol0;
    } else {
        int u = t - 1536; int kt = u >> 5, nt = u & 31;
        src = wo; dst = wo_f; C = 1024; K = 512; scale = 1.f;
        k0 = kt * 32; ncol0 = nt * 32; nglob0 = ncol0;
    }
    int ti = threadIdx.x >> 5, tj = threadIdx.x & 31;
#pragma unroll
    for (int p = 0; p < 4; ++p)
        tile[ti + 8 * p][tj] = src[(size_t)(k0 + ti + 8 * p) * C + ncol0 + tj] * scale;
    __syncthreads();
    if (threadIdx.x < 128) {
        int nl = threadIdx.x & 31, kc8 = threadIdx.x >> 5;
        union { ushort us[8]; uint4 v; } u;
#pragma unroll
        for (int ii = 0; ii < 8; ++ii) u.us[ii] = f2bf(tile[kc8 * 8 + ii][nl]);
        *(uint4*)&dst[frag_off(nglob0 + nl, k0 + kc8 * 8, K >> 5)] = u.v;
    }
}

// ---------------------------------------------------------------------------
// K2: fused finalize + normalize + cast to frag-major xn. grid 512, block 256.
__global__ __launch_bounds__(256) void finalize_norm(
    const float* __restrict__ ps, const float* __restrict__ pq,
    const float* __restrict__ x, const float* __restrict__ g,
    ushort* __restrict__ xnf) {
    __shared__ float s4[4][64], q4[4][64], aa[64], bb[64];
    int t = threadIdx.x;
    int b = blockIdx.x >> 8, slab = (blockIdx.x >> 4) & 15, nch = blockIdx.x & 15;
    int c0 = slab * 64;
    {
        int c = t & 63, grp = t >> 6;
        float s = 0.f, q = 0.f;
#pragma unroll
        for (int ch = 0; ch < 8; ++ch) {
            int o = (grp * 8 + ch) * 2048 + b * 1024 + c0 + c;
            s += ps[o]; q += pq[o];
        }
        s4[grp][c] = s; q4[grp][c] = q;
    }
    __syncthreads();
    if (t < 64) {
        float s = s4[0][t] + s4[1][t] + s4[2][t] + s4[3][t];
        float q = q4[0][t] + q4[1][t] + q4[2][t] + q4[3][t];
        float mean = s * (1.f / N_);
        float var = q * (1.f / N_) - mean * mean;
        float rstd = rsqrtf(var + 1e-5f);
        float a = rstd * g[c0 + t];
        aa[t] = a; bb[t] = -mean * a;
    }
    __syncthreads();
    int c4 = (t & 15) * 4, ro = t >> 4;
#pragma unroll
    for (int it = 0; it < 8; ++it) {
        int r = nch * 128 + it * 16 + ro;
        int m = b * 2048 + r;
        float4 xv = *(const float4*)&x[(size_t)m * DIM_ + c0 + c4];
        float v0 = xv.x * aa[c4 + 0] + bb[c4 + 0];
        float v1 = xv.y * aa[c4 + 1] + bb[c4 + 1];
        float v2 = xv.z * aa[c4 + 2] + bb[c4 + 2];
        float v3 = xv.w * aa[c4 + 3] + bb[c4 + 3];
        uint2 u; u.x = pkbf(v0, v1); u.y = pkbf(v2, v3);
        *(uint2*)&xnf[frag_off(m, c0 + c4, 32)] = u;
    }
}

// ---------------------------------------------------------------------------
// LDS-free GEMM core: ROLLED 3-stage register pipeline (round-10 win).
// Retained for K5 only.
template <int NKC>
__device__ __forceinline__ void gemm_core(
    const ushort* __restrict__ pA, const ushort* __restrict__ pB,
    floatx4 (&acc)[4][4]) {
    constexpr int TS = NKC * 512;
    bf16x8 a0[4], b0[4], a1[4], b1[4], a2[4], b2[4];
    auto ld = [&](bf16x8 (&a)[4], bf16x8 (&b)[4], int kc) {
#pragma unroll
        for (int i = 0; i < 4; ++i) {
            a[i] = *(const bf16x8*)(pA + (size_t)i * TS + (size_t)kc * 512);
            b[i] = *(const bf16x8*)(pB + (size_t)i * TS + (size_t)kc * 512);
        }
    };
    auto mm = [&](bf16x8 (&a)[4], bf16x8 (&b)[4]) {
#pragma unroll
        for (int mi = 0; mi < 4; ++mi)
#pragma unroll
            for (int ni = 0; ni < 4; ++ni)
                acc[mi][ni] = __builtin_amdgcn_mfma_f32_16x16x32_bf16(
                    a[mi], b[ni], acc[mi][ni], 0, 0, 0);
    };
    ld(a0, b0, 0);
    ld(a1, b1, 1);
    int kc = 0;
    for (; kc + 3 <= NKC; kc += 3) {
        ld(a2, b2, kc + 2);
        mm(a0, b0);
        if (kc + 3 < NKC) ld(a0, b0, kc + 3);
        mm(a1, b1);
        if (kc + 4 < NKC) ld(a1, b1, kc + 4);
        mm(a2, b2);
    }
    if (NKC % 3 >= 1) mm(a0, b0);     // stage kc
    if (NKC % 3 == 2) mm(a1, b1);     // stage kc+1
}

// K3: qkv GEMM, m97-structure. 1D grid 384, block 256 (4 waves, 2x2),
// 128x128 block tile, BK=32. Double-buffered LDS sAB[2][16][512]
// (chunks 0..7 = A row-tiles, 8..15 = B col-tiles; 32 KB). Wave w stages
// chunks w*4..w*4+3 via global_load_lds width=16 (chunk = 64 lanes x 16B
// contiguous in frag-major layout). One barrier per K-step (T3-minimum).
__global__ __launch_bounds__(256) void gemm_qkv(
    const ushort* __restrict__ xnf, const ushort* __restrict__ wf,
    ushort* __restrict__ qf, ushort* __restrict__ kf, ushort* __restrict__ vf) {
    __shared__ __align__(16) ushort sAB[2][16][512];
    int tx = threadIdx.x, w = tx >> 6, l = tx & 63;
    int wr = w >> 1, wc = w & 1;
    int lr = l & 15, lq = l >> 4;
    int bid = blockIdx.x;
    int xcd = bid & 7, t = bid >> 3;          // t: 0..47
    int bx = xcd * 4 + (t & 3);               // 0..31 (128-row slab)
    int by = t >> 2;                          // 0..11
    int rx = bx * 2 + wr;                     // 0..63 (64-row slab)

    // Per-wave staging sources (wave-uniform chunk ids, per-lane address).
    const ushort* gsrc[4];
#pragma unroll
    for (int c = 0; c < 4; ++c) {
        int ch = w * 4 + c;                   // 0..15
        gsrc[c] = (ch < 8)
            ? xnf + (size_t)(bx * 8 + ch) * (32 * 512) + l * 8
            : wf  + (size_t)(by * 8 + (ch - 8)) * (32 * 512) + l * 8;
    }
    auto stage = [&](int buf, int kc) {
#pragma unroll
        for (int c = 0; c < 4; ++c)
            gld_lds16(gsrc[c] + (size_t)kc * 512, &sAB[buf][w * 4 + c][0]);
    };

    floatx4 acc[4][4] = {};
    stage(0, 0);
    __syncthreads();
    int cur = 0;
    for (int kc = 0; kc < 32; ++kc) {
        if (kc + 1 < 32) stage(cur ^ 1, kc + 1);   // async prefetch next
        bf16x8 a[4], b[4];
#pragma unroll
        for (int i = 0; i < 4; ++i) {
            a[i] = *(const bf16x8*)&sAB[cur][wr * 4 + i][l * 8];
            b[i] = *(const bf16x8*)&sAB[cur][8 + wc * 4 + i][l * 8];
        }
#pragma unroll
        for (int mi = 0; mi < 4; ++mi)
#pragma unroll
            for (int ni = 0; ni < 4; ++ni)
                acc[mi][ni] = __builtin_amdgcn_mfma_f32_16x16x32_bf16(
                    a[mi], b[ni], acc[mi][ni], 0, 0, 0);
        __syncthreads();                           // drains vmcnt: next buf ready
        cur ^= 1;
    }

    int col0 = by * 128 + wc * 64;
    int bb2 = (rx * 64) >> 11;
    if (by < 8) {
        ushort* qkbase = (by < 4) ? qf : kf;
#pragma unroll
        for (int ni = 0; ni < 4; ++ni) {
            int col = col0 + 16 * ni + lr;
            int hh = (col >> 6) & 7, d = col & 63;
            ushort* base = qkbase + (size_t)(bb2 * 8 + hh) * BHSTRIDE
                           + (d >> 5) * 512 + ((d >> 3) & 3) * 128 + (d & 7)
                           + (4 * lq) * 8;
#pragma unroll
            for (int mi = 0; mi < 4; ++mi) {
                size_t o2 = (size_t)((rx * 4 + mi) & 127) * 1024;
#pragma unroll
                for (int reg = 0; reg < 4; ++reg)
                    base[o2 + reg * 8] = f2bf(acc[mi][ni][reg]);
            }
        }
    } else {
#pragma unroll
        for (int ni = 0; ni < 4; ++ni) {
            int cv = col0 - 1024 + 16 * ni + lr;
            int hh = cv >> 6, d = cv & 63;
            ushort* base = vf + (size_t)(bb2 * 8 + hh) * BHSTRIDE
                           + (d >> 4) * 32768 + (d & 15) * 8;
#pragma unroll
            for (int mi = 0; mi < 4; ++mi) {
                int nn = (rx * 64 + 16 * mi + 4 * lq) & 2047;
                uint2 u;
                u.x = pkbf(acc[mi][ni][0], acc[mi][ni][1]);
                u.y = pkbf(acc[mi][ni][2], acc[mi][ni][3]);
                *(uint2*)&base[(nn >> 5) * 512 + ((nn >> 3) & 3) * 128 + (nn & 7)] = u;
            }
        }
    }
}

// K5: out GEMM. 1D grid 256, block 256 (4 waves, 2x2): 128x128 per block.
__global__ __launch_bounds__(256) void gemm_out(
    const ushort* __restrict__ af, const ushort* __restrict__ wf,
    float* __restrict__ out) {
    int tx = threadIdx.x, w = tx >> 6, l = tx & 63;
    int wr = w >> 1, wc = w & 1;
    int lr = l & 15, lq = l >> 4;
    int bid = blockIdx.x;
    int xcd = bid & 7, t = bid >> 3;          // t: 0..31
    int bx = xcd * 4 + (t & 3);               // 0..31 (128-row slab)
    int by = t >> 2;                          // 0..7
    int rx = bx * 2 + wr;                     // 0..63
    const ushort* pA = af + (size_t)(rx * 4) * 16 * 512 + l * 8;
    const ushort* pB = wf + (size_t)(by * 8 + wc * 4) * 16 * 512 + l * 8;
    floatx4 acc[4][4] = {};
    gemm_core<16>(pA, pB, acc);
    int col0 = by * 128 + wc * 64;
#pragma unroll
    for (int mi = 0; mi < 4; ++mi)
#pragma unroll
        for (int ni = 0; ni < 4; ++ni) {
            int col = col0 + 16 * ni + lr;
#pragma unroll
            for (int reg = 0; reg < 4; ++reg) {
                int row = rx * 64 + 16 * mi + 4 * lq + reg;
                out[(size_t)row * 1024 + col] = acc[mi][ni][reg];
            }
        }
}

// ---------------------------------------------------------------------------
// K4: flash, 128 q-rows per block. 256 blocks x 512 thr (8 waves).
// Wave w: q-subtile qsel=w>>2 (64 rows), key-quarter kq=w&3 (512 keys).
__global__ __launch_bounds__(512, 2) void flash_attn(
    const ushort* __restrict__ qf, const ushort* __restrict__ kf,
    const ushort* __restrict__ vf, ushort* __restrict__ attnf) {
    __shared__ __align__(16) float sArena[8 * 4352];  // P (loop) / O 64x68 (merge)
    __shared__ float sL[8][64];

    const int tx = threadIdx.x;
    const int w = tx >> 6, l = tx & 63;      // w: 0..7
    const int qsel = w >> 2, kq = w & 3;
    const int lr = l & 15, lq = l >> 4;
    const int bid = blockIdx.x;              // 0..255
    const int bh = (bid & 7) * 2 + ((bid >> 3) & 1);
    const int qt = bid >> 4;                 // 0..15 (tile of 128 q rows)

    const ushort* qfb = qf + (size_t)bh * BHSTRIDE
                        + (size_t)(qt * 8 + qsel * 4) * 1024 + l * 8;
    const ushort* kfb = kf + (size_t)bh * BHSTRIDE + (size_t)kq * 32768 + l * 8;
    const ushort* vfb = vf + (size_t)bh * BHSTRIDE + (size_t)kq * 8192 + l * 8;
    ushort* sPw = (ushort*)(sArena + w * 4352);

    bf16x8 bq[4][2];
#pragma unroll
    for (int qq = 0; qq < 4; ++qq)
#pragma unroll
        for (int s = 0; s < 2; ++s)
            bq[qq][s] = *(const bf16x8*)(qfb + qq * 1024 + s * 512);

    floatx4 o[4][4] = {};
    float lsum[4] = {0.f, 0.f, 0.f, 0.f};

    bf16x8 ak[8], bv[8];
#pragma unroll
    for (int kk = 0; kk < 4; ++kk) {
        ak[kk * 2 + 0] = *(const bf16x8*)(kfb + kk * 1024);
        ak[kk * 2 + 1] = *(const bf16x8*)(kfb + kk * 1024 + 512);
    }

    for (int kt = 0; kt < 8; ++kt) {
#pragma unroll
        for (int dt = 0; dt < 4; ++dt) {
            bv[dt * 2 + 0] = *(const bf16x8*)(vfb + dt * 32768 + (kt * 2 + 0) * 512);
            bv[dt * 2 + 1] = *(const bf16x8*)(vfb + dt * 32768 + (kt * 2 + 1) * 512);
        }

        // QK^T + softmax-exp in two kk-halves (lsum order kk-ascending =
        // bitwise identical across rounds).
#pragma unroll
        for (int h = 0; h < 2; ++h) {
            floatx4 c[2][4] = {};
            __builtin_amdgcn_s_setprio(1);
#pragma unroll
            for (int s = 0; s < 2; ++s)
#pragma unroll
                for (int kk = 0; kk < 2; ++kk)
#pragma unroll
                    for (int qq = 0; qq < 4; ++qq)
                        c[kk][qq] = __builtin_amdgcn_mfma_f32_16x16x32_bf16(
                            ak[(2 * h + kk) * 2 + s], bq[qq][s], c[kk][qq], 0, 0, 0);
            __builtin_amdgcn_s_setprio(0);

            // ak dead after half 1's MFMAs: prefetch next K-tile here so the
            // loads' latency hides under half-1 exp + PV.
            if (h == 1 && kt + 1 < 8) {
                const ushort* kp = kfb + (size_t)(kt + 1) * 4096;
#pragma unroll
                for (int kk = 0; kk < 4; ++kk) {
                    ak[kk * 2 + 0] = *(const bf16x8*)(kp + kk * 1024);
                    ak[kk * 2 + 1] = *(const bf16x8*)(kp + kk * 1024 + 512);
                }
            }

#pragma unroll
            for (int kk = 0; kk < 2; ++kk)
#pragma unroll
                for (int qq = 0; qq < 4; ++qq) {
                    float e0 = EXP2(c[kk][qq][0]);
                    float e1 = EXP2(c[kk][qq][1]);
                    float e2 = EXP2(c[kk][qq][2]);
                    float e3 = EXP2(c[kk][qq][3]);
                    lsum[qq] += (e0 + e1) + (e2 + e3);
                    uint2 u; u.x = pkbf(e0, e1); u.y = pkbf(e2, e3);
                    *(uint2*)&sPw[(16 * qq + lr) * 72 + 16 * (2 * h + kk) + 4 * lq] = u;
                }
        }

#pragma unroll
        for (int s = 0; s < 2; ++s) {
            bf16x8 ap[4];
#pragma unroll
            for (int mi = 0; mi < 4; ++mi)
                ap[mi] = *(const bf16x8*)&sPw[(16 * mi + lr) * 72 + 32 * s + 8 * lq];
            __builtin_amdgcn_s_setprio(1);
#pragma unroll
            for (int mi = 0; mi < 4; ++mi)
#pragma unroll
                for (int dt = 0; dt < 4; ++dt)
                    o[mi][dt] = __builtin_amdgcn_mfma_f32_16x16x32_bf16(
                        ap[mi], bv[dt * 2 + s], o[mi][dt], 0, 0, 0);
            __builtin_amdgcn_s_setprio(0);
        }
    }

#pragma unroll
    for (int qq = 0; qq < 4; ++qq) {
        lsum[qq] += __shfl_xor(lsum[qq], 16);
        lsum[qq] += __shfl_xor(lsum[qq], 32);
    }

    float* Rw = sArena + w * 4352;
#pragma unroll
    for (int mi = 0; mi < 4; ++mi)
#pragma unroll
        for (int dt = 0; dt < 4; ++dt)
#pragma unroll
            for (int reg = 0; reg < 4; ++reg)
                Rw[(16 * mi + 4 * lq + reg) * 68 + 16 * dt + lr] = o[mi][dt][reg];
    if (lq == 0) {
#pragma unroll
        for (int qq = 0; qq < 4; ++qq) sL[w][16 * qq + lr] = lsum[qq];
    }
    __syncthreads();

    // Merge group g = qsel handles q-subtile g: arenas g*4 + rg, rg = 0..3
    // (same key-quarter order -> identical summation order).
    const int g = qsel;
    int qloc = 16 * (w & 3) + (l >> 2);
    int c0 = (l & 3) * 16;
    float4 acc[4];
#pragma unroll
    for (int rg = 0; rg < 4; ++rg) {
        const float* R = sArena + (g * 4 + rg) * 4352 + qloc * 68 + c0;
#pragma unroll
        for (int c = 0; c < 4; ++c) {
            float4 v = *(const float4*)&R[4 * c];
            if (rg == 0) acc[c] = v;
            else { acc[c].x += v.x; acc[c].y += v.y; acc[c].z += v.z; acc[c].w += v.w; }
        }
    }
    float ltot = sL[g * 4 + 0][qloc] + sL[g * 4 + 1][qloc]
               + sL[g * 4 + 2][qloc] + sL[g * 4 + 3][qloc];
    float inv = 1.f / ltot;
    int m = (bh >> 3) * 2048 + qt * 128 + g * 64 + qloc;
    int kb = (bh & 7) * 64 + c0;
#pragma unroll
    for (int c = 0; c < 4; ++c) {
        uint2 u;
        u.x = pkbf(acc[c].x * inv, acc[c].y * inv);
        u.y = pkbf(acc[c].z * inv, acc[c].w * inv);
        *(uint2*)&attnf[frag_off(m, kb + 4 * c, 16)] = u;
    }
}

// ---------------------------------------------------------------------------
extern "C" void kernel_launch(void* const* d_in, const int* in_sizes, int n_in,
                              void* d_out, int out_size, void* d_ws, size_t ws_size,
                              hipStream_t stream) {
    const float* x   = (const float*)d_in[0];
    const float* g   = (const float*)d_in[1];
    const float* wq  = (const float*)d_in[2];
    const float* wkv = (const float*)d_in[3];
    const float* wo  = (const float*)d_in[4];
    float* out = (float*)d_out;

    char* ws = (char*)d_ws;
    float*  psum   = (float*)(ws + 0);          // 256K
    float*  psqr   = (float*)(ws + 262144);     // 256K
    ushort* xnf    = (ushort*)(ws + 524288);    // 8.39M frag-major K=1024
    ushort* wqkv_f = (ushort*)(ws + 8912896);   // 3.15M frag-major K=1024
    ushort* wo_f   = (ushort*)(ws + 12058624);  // 1.05M frag-major K=512
    ushort* qfb    = (ushort*)(ws + 13107200);  // 4.19M per-bh frag [row][d]
    ushort* kfb    = (ushort*)(ws + 17301504);  // 4.19M per-bh frag [row][d]
    ushort* vfb    = (ushort*)(ws + 21495808);  // 4.19M per-bh frag [d][key]
    ushort* attnf  = (ushort*)(ws + 25690112);  // 4.19M frag-major K=512

    setup_fused<<<2304, 256, 0, stream>>>(x, psum, psqr, wq, wkv, wo, wqkv_f, wo_f);
    finalize_norm<<<512, 256, 0, stream>>>(psum, psqr, x, g, xnf);
    gemm_qkv<<<384, 256, 0, stream>>>(xnf, wqkv_f, qfb, kfb, vfb);
    flash_attn<<<256, 512, 0, stream>>>(qfb, kfb, vfb, attnf);
    gemm_out<<<256, 256, 0, stream>>>(attnf, wo_f, out);
}

// Round 12
// 140.026 us; speedup vs baseline: 1.1075x; 1.0200x over previous
//
#include <hip/hip_runtime.h>
#include <hip/hip_bf16.h>
#include <stdint.h>

// B=2, N=2048, DIM=1024, HEADS=8, DIM_HEAD=64, INNER=512
// Round 20: REVERT to round-14 (best measured 140.4us) + ONE safe change:
// K1 stats loop unroll 16 -> 64 (same mechanism as the proven round-12 win:
// MLP 16->64 outstanding loads, latency batches 4 -> 1; serial add chain
// preserved -> bitwise-identical output, absmax exactly 1.831e-4).
// K3 ledger closed after 4 structural attempts (reg-3stage best; -tile +6,
// 4-stage +15, gload_lds 2-phase +2.4): at 1.5 blocks/CU there is no TLP
// to cover barrier drains, and all structures converge to ~25us.
// ~82us of dur_us is harness poison-fill pedestal (round-15 probe).

#define B_ 2
#define N_ 2048
#define DIM_ 1024
#define DH_ 64
#define INNER_ 512
#define ROWS_ 4096
#define BHSTRIDE 131072    // 2048*64 elems per (b,h) for qf/kf/vf

// q scale 1/8 (=DH^-0.5) * log2(e), folded into wq cast; kernel uses exp2.
#define QSCALE 0.18033688011112042f

typedef __bf16 bf16x8 __attribute__((ext_vector_type(8)));
typedef float floatx4 __attribute__((ext_vector_type(4)));

#if __has_builtin(__builtin_amdgcn_exp2f)
#define EXP2(x) __builtin_amdgcn_exp2f(x)
#else
#define EXP2(x) exp2f(x)
#endif

// HW bf16 conversion (RNE).
__device__ __forceinline__ ushort f2bf(float f) {
    union { __bf16 h; ushort u; } v;
    v.h = (__bf16)f;
    return v.u;
}
#if __has_builtin(__builtin_amdgcn_cvt_pk_bf16_f32)
__device__ __forceinline__ uint32_t pkbf(float a, float b) {
    auto h = __builtin_amdgcn_cvt_pk_bf16_f32(a, b);
    union { decltype(h) h; uint32_t u; } v;
    v.h = h;
    return v.u;
}
#else
__device__ __forceinline__ uint32_t pkbf(float a, float b) {
    return (uint32_t)f2bf(a) | ((uint32_t)f2bf(b) << 16);
}
#endif

// frag-major element offset: lane l of a wave holds M=16*T+(l&15),
// k = 32*kc + 8*(l>>4) + j  (j=0..7). nkc = K/32.
__device__ __forceinline__ size_t frag_off(int m, int k, int nkc) {
    return ((size_t)((m >> 4) * nkc + (k >> 5)) * 64 +
            (size_t)((m & 15) | (((k >> 3) & 3) << 4))) * 8 + (k & 7);
}

// ---------------------------------------------------------------------------
// K1: fused setup. blocks 0..255: partial column stats (seq axis).
// blocks 256..2303: weight cast into frag-major layouts.
__global__ __launch_bounds__(256) void setup_fused(
    const float* __restrict__ x, float* __restrict__ ps, float* __restrict__ pq,
    const float* __restrict__ wq, const float* __restrict__ wkv,
    const float* __restrict__ wo, ushort* __restrict__ wqkv_f,
    ushort* __restrict__ wo_f) {
    __shared__ float tile[32][33];
    int bid = blockIdx.x;
    if (bid < 256) {
        int gd = (bid & 7) * 256 + threadIdx.x;   // b*1024 + c
        int ch = bid >> 3;                        // 0..31
        int b = gd >> 10;
        const float* p = x + (size_t)(b * N_ + ch * 64) * DIM_ + (gd & 1023);
        float s = 0.f, q = 0.f;
#pragma unroll 64
        for (int n = 0; n < 64; ++n) { float v = p[(size_t)n * DIM_]; s += v; q += v * v; }
        ps[ch * 2048 + gd] = s;
        pq[ch * 2048 + gd] = q;
        return;
    }
    int t = bid - 256;
    const float* src; ushort* dst; int C, K, k0, ncol0, nglob0; float scale;
    if (t < 512) {
        int kt = t >> 4, nt = t & 15;
        src = wq; dst = wqkv_f; C = 512; K = 1024; scale = QSCALE;
        k0 = kt * 32; ncol0 = nt * 32; nglob0 = ncol0;
    } else if (t < 1536) {
        int u = t - 512; int kt = u >> 5, nt = u & 31;
        src = wkv; dst = wqkv_f; C = 1024; K = 1024; scale = 1.f;
        k0 = kt * 32; ncol0 = nt * 32; nglob0 = 512 + ncol0;
    } else {
        int u = t - 1536; int kt = u >> 5, nt = u & 31;
        src = wo; dst = wo_f; C = 1024; K = 512; scale = 1.f;
        k0 = kt * 32; ncol0 = nt * 32; nglob0 = ncol0;
    }
    int ti = threadIdx.x >> 5, tj = threadIdx.x & 31;
#pragma unroll
    for (int p = 0; p < 4; ++p)
        tile[ti + 8 * p][tj] = src[(size_t)(k0 + ti + 8 * p) * C + ncol0 + tj] * scale;
    __syncthreads();
    if (threadIdx.x < 128) {
        int nl = threadIdx.x & 31, kc8 = threadIdx.x >> 5;
        union { ushort us[8]; uint4 v; } u;
#pragma unroll
        for (int ii = 0; ii < 8; ++ii) u.us[ii] = f2bf(tile[kc8 * 8 + ii][nl]);
        *(uint4*)&dst[frag_off(nglob0 + nl, k0 + kc8 * 8, K >> 5)] = u.v;
    }
}

// ---------------------------------------------------------------------------
// K2: fused finalize + normalize + cast to frag-major xn. grid 512, block 256.
__global__ __launch_bounds__(256) void finalize_norm(
    const float* __restrict__ ps, const float* __restrict__ pq,
    const float* __restrict__ x, const float* __restrict__ g,
    ushort* __restrict__ xnf) {
    __shared__ float s4[4][64], q4[4][64], aa[64], bb[64];
    int t = threadIdx.x;
    int b = blockIdx.x >> 8, slab = (blockIdx.x >> 4) & 15, nch = blockIdx.x & 15;
    int c0 = slab * 64;
    {
        int c = t & 63, grp = t >> 6;
        float s = 0.f, q = 0.f;
#pragma unroll
        for (int ch = 0; ch < 8; ++ch) {
            int o = (grp * 8 + ch) * 2048 + b * 1024 + c0 + c;
            s += ps[o]; q += pq[o];
        }
        s4[grp][c] = s; q4[grp][c] = q;
    }
    __syncthreads();
    if (t < 64) {
        float s = s4[0][t] + s4[1][t] + s4[2][t] + s4[3][t];
        float q = q4[0][t] + q4[1][t] + q4[2][t] + q4[3][t];
        float mean = s * (1.f / N_);
        float var = q * (1.f / N_) - mean * mean;
        float rstd = rsqrtf(var + 1e-5f);
        float a = rstd * g[c0 + t];
        aa[t] = a; bb[t] = -mean * a;
    }
    __syncthreads();
    int c4 = (t & 15) * 4, ro = t >> 4;
#pragma unroll
    for (int it = 0; it < 8; ++it) {
        int r = nch * 128 + it * 16 + ro;
        int m = b * 2048 + r;
        float4 xv = *(const float4*)&x[(size_t)m * DIM_ + c0 + c4];
        float v0 = xv.x * aa[c4 + 0] + bb[c4 + 0];
        float v1 = xv.y * aa[c4 + 1] + bb[c4 + 1];
        float v2 = xv.z * aa[c4 + 2] + bb[c4 + 2];
        float v3 = xv.w * aa[c4 + 3] + bb[c4 + 3];
        uint2 u; u.x = pkbf(v0, v1); u.y = pkbf(v2, v3);
        *(uint2*)&xnf[frag_off(m, c0 + c4, 32)] = u;
    }
}

// ---------------------------------------------------------------------------
// LDS-free GEMM core: ROLLED 3-stage register pipeline (round-10 win).
template <int NKC>
__device__ __forceinline__ void gemm_core(
    const ushort* __restrict__ pA, const ushort* __restrict__ pB,
    floatx4 (&acc)[4][4]) {
    constexpr int TS = NKC * 512;
    bf16x8 a0[4], b0[4], a1[4], b1[4], a2[4], b2[4];
    auto ld = [&](bf16x8 (&a)[4], bf16x8 (&b)[4], int kc) {
#pragma unroll
        for (int i = 0; i < 4; ++i) {
            a[i] = *(const bf16x8*)(pA + (size_t)i * TS + (size_t)kc * 512);
            b[i] = *(const bf16x8*)(pB + (size_t)i * TS + (size_t)kc * 512);
        }
    };
    auto mm = [&](bf16x8 (&a)[4], bf16x8 (&b)[4]) {
#pragma unroll
        for (int mi = 0; mi < 4; ++mi)
#pragma unroll
            for (int ni = 0; ni < 4; ++ni)
                acc[mi][ni] = __builtin_amdgcn_mfma_f32_16x16x32_bf16(
                    a[mi], b[ni], acc[mi][ni], 0, 0, 0);
    };
    ld(a0, b0, 0);
    ld(a1, b1, 1);
    int kc = 0;
    for (; kc + 3 <= NKC; kc += 3) {
        ld(a2, b2, kc + 2);
        mm(a0, b0);
        if (kc + 3 < NKC) ld(a0, b0, kc + 3);
        mm(a1, b1);
        if (kc + 4 < NKC) ld(a1, b1, kc + 4);
        mm(a2, b2);
    }
    if (NKC % 3 >= 1) mm(a0, b0);     // stage kc
    if (NKC % 3 == 2) mm(a1, b1);     // stage kc+1
}

// K3: qkv GEMM. 1D grid 384, block 256 (4 waves, 2x2): 128 rows x 128 cols
// per block; waves pair-share A (wc pair) and B (wr pair) via L1.
// XCD swizzle: XCD j owns bx slab j*4..j*4+3.
__global__ __launch_bounds__(256) void gemm_qkv(
    const ushort* __restrict__ xnf, const ushort* __restrict__ wf,
    ushort* __restrict__ qf, ushort* __restrict__ kf, ushort* __restrict__ vf) {
    int tx = threadIdx.x, w = tx >> 6, l = tx & 63;
    int wr = w >> 1, wc = w & 1;
    int lr = l & 15, lq = l >> 4;
    int bid = blockIdx.x;
    int xcd = bid & 7, t = bid >> 3;          // t: 0..47
    int bx = xcd * 4 + (t & 3);               // 0..31 (128-row slab)
    int by = t >> 2;                          // 0..11
    int rx = bx * 2 + wr;                     // 0..63 (64-row slab, = old bx)
    const ushort* pA = xnf + (size_t)(rx * 4) * 32 * 512 + l * 8;
    const ushort* pB = wf + (size_t)(by * 8 + wc * 4) * 32 * 512 + l * 8;
    floatx4 acc[4][4] = {};
    gemm_core<32>(pA, pB, acc);
    int col0 = by * 128 + wc * 64;
    int bb2 = (rx * 64) >> 11;
    if (by < 8) {
        ushort* qkbase = (by < 4) ? qf : kf;
#pragma unroll
        for (int ni = 0; ni < 4; ++ni) {
            int col = col0 + 16 * ni + lr;
            int hh = (col >> 6) & 7, d = col & 63;
            ushort* base = qkbase + (size_t)(bb2 * 8 + hh) * BHSTRIDE
                           + (d >> 5) * 512 + ((d >> 3) & 3) * 128 + (d & 7)
                           + (4 * lq) * 8;
#pragma unroll
            for (int mi = 0; mi < 4; ++mi) {
                size_t o2 = (size_t)((rx * 4 + mi) & 127) * 1024;
#pragma unroll
                for (int reg = 0; reg < 4; ++reg)
                    base[o2 + reg * 8] = f2bf(acc[mi][ni][reg]);
            }
        }
    } else {
#pragma unroll
        for (int ni = 0; ni < 4; ++ni) {
            int cv = col0 - 1024 + 16 * ni + lr;
            int hh = cv >> 6, d = cv & 63;
            ushort* base = vf + (size_t)(bb2 * 8 + hh) * BHSTRIDE
                           + (d >> 4) * 32768 + (d & 15) * 8;
#pragma unroll
            for (int mi = 0; mi < 4; ++mi) {
                int nn = (rx * 64 + 16 * mi + 4 * lq) & 2047;
                uint2 u;
                u.x = pkbf(acc[mi][ni][0], acc[mi][ni][1]);
                u.y = pkbf(acc[mi][ni][2], acc[mi][ni][3]);
                *(uint2*)&base[(nn >> 5) * 512 + ((nn >> 3) & 3) * 128 + (nn & 7)] = u;
            }
        }
    }
}

// K5: out GEMM. 1D grid 256, block 256 (4 waves, 2x2): 128x128 per block.
__global__ __launch_bounds__(256) void gemm_out(
    const ushort* __restrict__ af, const ushort* __restrict__ wf,
    float* __restrict__ out) {
    int tx = threadIdx.x, w = tx >> 6, l = tx & 63;
    int wr = w >> 1, wc = w & 1;
    int lr = l & 15, lq = l >> 4;
    int bid = blockIdx.x;
    int xcd = bid & 7, t = bid >> 3;          // t: 0..31
    int bx = xcd * 4 + (t & 3);               // 0..31 (128-row slab)
    int by = t >> 2;                          // 0..7
    int rx = bx * 2 + wr;                     // 0..63 (= old bx)
    const ushort* pA = af + (size_t)(rx * 4) * 16 * 512 + l * 8;
    const ushort* pB = wf + (size_t)(by * 8 + wc * 4) * 16 * 512 + l * 8;
    floatx4 acc[4][4] = {};
    gemm_core<16>(pA, pB, acc);
    int col0 = by * 128 + wc * 64;
#pragma unroll
    for (int mi = 0; mi < 4; ++mi)
#pragma unroll
        for (int ni = 0; ni < 4; ++ni) {
            int col = col0 + 16 * ni + lr;
#pragma unroll
            for (int reg = 0; reg < 4; ++reg) {
                int row = rx * 64 + 16 * mi + 4 * lq + reg;
                out[(size_t)row * 1024 + col] = acc[mi][ni][reg];
            }
        }
}

// ---------------------------------------------------------------------------
// K4: flash, 128 q-rows per block. 256 blocks x 512 thr (8 waves).
// Wave w: q-subtile qsel=w>>2 (64 rows), key-quarter kq=w&3 (512 keys).
// Merge: two independent 4-way merges; group g=w>>2 reads arenas g*4+rg
// in the same rg order -> bitwise-identical sums.
__global__ __launch_bounds__(512, 2) void flash_attn(
    const ushort* __restrict__ qf, const ushort* __restrict__ kf,
    const ushort* __restrict__ vf, ushort* __restrict__ attnf) {
    __shared__ __align__(16) float sArena[8 * 4352];  // P (loop) / O 64x68 (merge)
    __shared__ float sL[8][64];

    const int tx = threadIdx.x;
    const int w = tx >> 6, l = tx & 63;      // w: 0..7
    const int qsel = w >> 2, kq = w & 3;
    const int lr = l & 15, lq = l >> 4;
    const int bid = blockIdx.x;              // 0..255
    const int bh = (bid & 7) * 2 + ((bid >> 3) & 1);
    const int qt = bid >> 4;                 // 0..15 (tile of 128 q rows)

    const ushort* qfb = qf + (size_t)bh * BHSTRIDE
                        + (size_t)(qt * 8 + qsel * 4) * 1024 + l * 8;
    const ushort* kfb = kf + (size_t)bh * BHSTRIDE + (size_t)kq * 32768 + l * 8;
    const ushort* vfb = vf + (size_t)bh * BHSTRIDE + (size_t)kq * 8192 + l * 8;
    ushort* sPw = (ushort*)(sArena + w * 4352);

    bf16x8 bq[4][2];
#pragma unroll
    for (int qq = 0; qq < 4; ++qq)
#pragma unroll
        for (int s = 0; s < 2; ++s)
            bq[qq][s] = *(const bf16x8*)(qfb + qq * 1024 + s * 512);

    floatx4 o[4][4] = {};
    float lsum[4] = {0.f, 0.f, 0.f, 0.f};

    bf16x8 ak[8], bv[8];
#pragma unroll
    for (int kk = 0; kk < 4; ++kk) {
        ak[kk * 2 + 0] = *(const bf16x8*)(kfb + kk * 1024);
        ak[kk * 2 + 1] = *(const bf16x8*)(kfb + kk * 1024 + 512);
    }

    for (int kt = 0; kt < 8; ++kt) {
#pragma unroll
        for (int dt = 0; dt < 4; ++dt) {
            bv[dt * 2 + 0] = *(const bf16x8*)(vfb + dt * 32768 + (kt * 2 + 0) * 512);
            bv[dt * 2 + 1] = *(const bf16x8*)(vfb + dt * 32768 + (kt * 2 + 1) * 512);
        }

        // QK^T + softmax-exp in two kk-halves (lsum order kk-ascending =
        // bitwise identical across rounds).
#pragma unroll
        for (int h = 0; h < 2; ++h) {
            floatx4 c[2][4] = {};
            __builtin_amdgcn_s_setprio(1);
#pragma unroll
            for (int s = 0; s < 2; ++s)
#pragma unroll
                for (int kk = 0; kk < 2; ++kk)
#pragma unroll
                    for (int qq = 0; qq < 4; ++qq)
                        c[kk][qq] = __builtin_amdgcn_mfma_f32_16x16x32_bf16(
                            ak[(2 * h + kk) * 2 + s], bq[qq][s], c[kk][qq], 0, 0, 0);
            __builtin_amdgcn_s_setprio(0);

            // ak dead after half 1's MFMAs: prefetch next K-tile here so the
            // loads' latency hides under half-1 exp + PV.
            if (h == 1 && kt + 1 < 8) {
                const ushort* kp = kfb + (size_t)(kt + 1) * 4096;
#pragma unroll
                for (int kk = 0; kk < 4; ++kk) {
                    ak[kk * 2 + 0] = *(const bf16x8*)(kp + kk * 1024);
                    ak[kk * 2 + 1] = *(const bf16x8*)(kp + kk * 1024 + 512);
                }
            }

#pragma unroll
            for (int kk = 0; kk < 2; ++kk)
#pragma unroll
                for (int qq = 0; qq < 4; ++qq) {
                    float e0 = EXP2(c[kk][qq][0]);
                    float e1 = EXP2(c[kk][qq][1]);
                    float e2 = EXP2(c[kk][qq][2]);
                    float e3 = EXP2(c[kk][qq][3]);
                    lsum[qq] += (e0 + e1) + (e2 + e3);
                    uint2 u; u.x = pkbf(e0, e1); u.y = pkbf(e2, e3);
                    *(uint2*)&sPw[(16 * qq + lr) * 72 + 16 * (2 * h + kk) + 4 * lq] = u;
                }
        }

#pragma unroll
        for (int s = 0; s < 2; ++s) {
            bf16x8 ap[4];
#pragma unroll
            for (int mi = 0; mi < 4; ++mi)
                ap[mi] = *(const bf16x8*)&sPw[(16 * mi + lr) * 72 + 32 * s + 8 * lq];
            __builtin_amdgcn_s_setprio(1);
#pragma unroll
            for (int mi = 0; mi < 4; ++mi)
#pragma unroll
                for (int dt = 0; dt < 4; ++dt)
                    o[mi][dt] = __builtin_amdgcn_mfma_f32_16x16x32_bf16(
                        ap[mi], bv[dt * 2 + s], o[mi][dt], 0, 0, 0);
            __builtin_amdgcn_s_setprio(0);
        }
    }

#pragma unroll
    for (int qq = 0; qq < 4; ++qq) {
        lsum[qq] += __shfl_xor(lsum[qq], 16);
        lsum[qq] += __shfl_xor(lsum[qq], 32);
    }

    float* Rw = sArena + w * 4352;
#pragma unroll
    for (int mi = 0; mi < 4; ++mi)
#pragma unroll
        for (int dt = 0; dt < 4; ++dt)
#pragma unroll
            for (int reg = 0; reg < 4; ++reg)
                Rw[(16 * mi + 4 * lq + reg) * 68 + 16 * dt + lr] = o[mi][dt][reg];
    if (lq == 0) {
#pragma unroll
        for (int qq = 0; qq < 4; ++qq) sL[w][16 * qq + lr] = lsum[qq];
    }
    __syncthreads();

    // Merge group g = qsel handles q-subtile g: arenas g*4 + rg, rg = 0..3
    // (same key-quarter order -> identical summation order).
    const int g = qsel;
    int qloc = 16 * (w & 3) + (l >> 2);
    int c0 = (l & 3) * 16;
    float4 acc[4];
#pragma unroll
    for (int rg = 0; rg < 4; ++rg) {
        const float* R = sArena + (g * 4 + rg) * 4352 + qloc * 68 + c0;
#pragma unroll
        for (int c = 0; c < 4; ++c) {
            float4 v = *(const float4*)&R[4 * c];
            if (rg == 0) acc[c] = v;
            else { acc[c].x += v.x; acc[c].y += v.y; acc[c].z += v.z; acc[c].w += v.w; }
        }
    }
    float ltot = sL[g * 4 + 0][qloc] + sL[g * 4 + 1][qloc]
               + sL[g * 4 + 2][qloc] + sL[g * 4 + 3][qloc];
    float inv = 1.f / ltot;
    int m = (bh >> 3) * 2048 + qt * 128 + g * 64 + qloc;
    int kb = (bh & 7) * 64 + c0;
#pragma unroll
    for (int c = 0; c < 4; ++c) {
        uint2 u;
        u.x = pkbf(acc[c].x * inv, acc[c].y * inv);
        u.y = pkbf(acc[c].z * inv, acc[c].w * inv);
        *(uint2*)&attnf[frag_off(m, kb + 4 * c, 16)] = u;
    }
}

// ---------------------------------------------------------------------------
extern "C" void kernel_launch(void* const* d_in, const int* in_sizes, int n_in,
                              void* d_out, int out_size, void* d_ws, size_t ws_size,
                              hipStream_t stream) {
    const float* x   = (const float*)d_in[0];
    const float* g   = (const float*)d_in[1];
    const float* wq  = (const float*)d_in[2];
    const float* wkv = (const float*)d_in[3];
    const float* wo  = (const float*)d_in[4];
    float* out = (float*)d_out;

    char* ws = (char*)d_ws;
    float*  psum   = (float*)(ws + 0);          // 256K
    float*  psqr   = (float*)(ws + 262144);     // 256K
    ushort* xnf    = (ushort*)(ws + 524288);    // 8.39M frag-major K=1024
    ushort* wqkv_f = (ushort*)(ws + 8912896);   // 3.15M frag-major K=1024
    ushort* wo_f   = (ushort*)(ws + 12058624);  // 1.05M frag-major K=512
    ushort* qfb    = (ushort*)(ws + 13107200);  // 4.19M per-bh frag [row][d]
    ushort* kfb    = (ushort*)(ws + 17301504);  // 4.19M per-bh frag [row][d]
    ushort* vfb    = (ushort*)(ws + 21495808);  // 4.19M per-bh frag [d][key]
    ushort* attnf  = (ushort*)(ws + 25690112);  // 4.19M frag-major K=512

    setup_fused<<<2304, 256, 0, stream>>>(x, psum, psqr, wq, wkv, wo, wqkv_f, wo_f);
    finalize_norm<<<512, 256, 0, stream>>>(psum, psqr, x, g, xnf);
    gemm_qkv<<<384, 256, 0, stream>>>(xnf, wqkv_f, qfb, kfb, vfb);
    flash_attn<<<256, 512, 0, stream>>>(qfb, kfb, vfb, attnf);
    gemm_out<<<256, 256, 0, stream>>>(attnf, wo_f, out);
}